// Round 18
// baseline (120.154 us; speedup 1.0000x reference)
//
#include <hip/hip_runtime.h>
#include <hip/hip_bf16.h>

#define NBLK  50000
#define NATOM 400000
#define NEDGE 800000
#define CAP   40               // max tracked in-edges per mol

typedef __bf16 bf16x8 __attribute__((ext_vector_type(8)));
typedef float  f32x4  __attribute__((ext_vector_type(4)));

// ---- workspace layout (bytes); total 17,719,712 < proven 18,403,840 ----
#define MCNT_OFF 0UL           // int32[50000]: per-mol edge cursors (memset 0)
#define EW1_OFF  200000UL      // f32[100][128] = emb@W1+b1
#define REC_OFF  251200UL      // u16[50000][40]: (pair*8 + dst&7), direct slots
#define T_OFF    4251200UL     // f32[500][128]: msg table; REWRITTEN to TW1 = T@W1
#define PW_OFF   4507200UL     // bf16[1024][128]: sinusoid @ W0[0:128]
#define W2T_OFF  4769344UL     // bf16[128][128]: (rs8*W2@W0[128:256])^T [n][k]
#define M1T_OFF  4802112UL     // bf16[128][128] mlp_w1^T
#define M2T_OFF  4834880UL     // bf16[128][128] mlp_w2^T
#define AAW_OFF  4867648UL     // f32[4][128]
#define GM_OFF   4869696UL     // u8[50000]
#define FLAG_OFF 4919696UL     // int32 sniff flag
#define TOPO_OFF 4919712UL     // bf16[50000][128] topo_pre
#define WS_NEED  18403840UL

#define RS8 0.35355339059327373f

#define MFMA(a,b,c) __builtin_amdgcn_mfma_f32_16x16x32_bf16((a),(b),(c),0,0,0)

__device__ inline f32x4 splat4(float v){ f32x4 r; r[0]=v; r[1]=v; r[2]=v; r[3]=v; return r; }
__device__ inline float scrub(float v){ return (v==v && v<1e30f && v>-1e30f) ? v : 0.f; }

// ---------------- dtype sniff for generate_mask (1 block) ----------------
__global__ void k_sniff(const void* gm_raw, char* ws) {
  __shared__ int big;
  if (threadIdx.x == 0) big = 0;
  __syncthreads();
  const unsigned* gw = (const unsigned*)gm_raw;
  for (int i = threadIdx.x; i < 12500; i += 256)
    if (gw[i] > 1u) big = 1;
  __syncthreads();
  if (threadIdx.x == 0) *(int*)(ws + FLAG_OFF) = big;
}

// ---- prep: T, M1T/M2T transposes, gm canon, SCATTER ----
// blocks: [0,100) T, [100,116) transposes, [116,166) gm, [166,948) scatter
__global__ void k_prep(const float* atom_embed, const float* bond_embed,
                       const float* m1, const float* m2,
                       const void* gm_raw, const int* __restrict__ bonds,
                       const int* __restrict__ A, char* ws) {
  int b = blockIdx.x, t = threadIdx.x;
  if (b < 100) {                       // T[a*5+bond][c] = relu(ae + be), f32
    float ae = atom_embed[b*128 + t];
    float* T = (float*)(ws + T_OFF);
    for (int bo = 0; bo < 5; ++bo) {
      float v = ae + bond_embed[bo*128 + t];
      T[(b*5 + bo)*128 + t] = v > 0.f ? v : 0.f;
    }
  } else if (b < 116) {                // weight transposes f32 -> bf16 [n][k]
    int wb = b - 100;
    const float* src; __bf16* dst; int r0;
    if (wb < 8) { src = m1; dst = (__bf16*)(ws + M1T_OFF); r0 = wb*16; }
    else        { src = m2; dst = (__bf16*)(ws + M2T_OFF); r0 = (wb-8)*16; }
    for (int rr = 0; rr < 16; ++rr) {
      int r = r0 + rr;
      dst[t*128 + r] = (__bf16)src[r*128 + t];
    }
  } else if (b < 166) {                // gm canon: 50 blocks x 1000 elems
    int anyBig = *(const int*)(ws + FLAG_OFF);
    int base = (b - 116) * 1000;
    unsigned char* gu = (unsigned char*)(ws + GM_OFF);
    if (anyBig) {
      const unsigned char* gb = (const unsigned char*)gm_raw;
      for (int i = t; i < 1000; i += 128) gu[base+i] = gb[base+i] ? 1 : 0;
    } else {
      const int* gi = (const int*)gm_raw;
      for (int i = t; i < 1000; i += 128) gu[base+i] = gi[base+i] ? 1 : 0;
    }
  } else {                             // SCATTER: 8 edges/thread, raw gm reads
    int anyBig = *(const int*)(ws + FLAG_OFF);
    const unsigned char* g8 = (const unsigned char*)gm_raw;
    const int* g32 = (const int*)gm_raw;
    long base = ((long)(b - 166)*128 + t)*8;
    #pragma unroll 2
    for (int h = 0; h < 2; ++h) {
      long e4 = base + h*4;
      if (e4 >= NEDGE) break;
      const int4* bp = (const int4*)(bonds + e4*3);
      int4 w0 = bp[0], w1 = bp[1], w2 = bp[2];
      int srcs[4] = {w0.x, w0.w, w1.z, w2.y};
      int dsts[4] = {w0.y, w1.x, w1.w, w2.z};
      int bts[4]  = {w0.z, w1.y, w2.x, w2.w};
      #pragma unroll
      for (int i = 0; i < 4; ++i) {
        int sm_ = srcs[i] >> 3, dm = dsts[i] >> 3;
        int bad = anyBig ? ((int)g8[sm_] | (int)g8[dm]) : (g32[sm_] | g32[dm]);
        if (bad) continue;
        int slot = atomicAdd((int*)(ws + MCNT_OFF) + dm, 1);
        if (slot >= 0 && slot < CAP)
          ((unsigned short*)(ws + REC_OFF))[dm*CAP + slot] =
            (unsigned short)((A[srcs[i]]*5 + bts[i])*8 + (dsts[i] & 7));
      }
    }
  }
}

// ------- prep2: EW1 = emb@W1+b1, TW1 = T@W1 (in place over T) -------
__global__ void k_prep2(const float* atom_embed, const float* g1, const float* gb1,
                        char* ws) {
  int b = blockIdx.x, t = threadIdx.x;
  float s0 = 0.f, s1 = 0.f, s2 = 0.f, s3 = 0.f;
  const float* row = (b < 100) ? (atom_embed + b*128) : ((float*)(ws + T_OFF) + (b-100)*128);
  #pragma unroll 4
  for (int k = 0; k < 128; k += 4) {
    s0 += row[k+0] * g1[(k+0)*128 + t];
    s1 += row[k+1] * g1[(k+1)*128 + t];
    s2 += row[k+2] * g1[(k+2)*128 + t];
    s3 += row[k+3] * g1[(k+3)*128 + t];
  }
  float s = (s0 + s1) + (s2 + s3);
  if (b < 100) {
    ((float*)(ws + EW1_OFF))[b*128 + t] = s + gb1[t];
  } else {
    __syncthreads();
    ((float*)(ws + T_OFF))[(b-100)*128 + t] = s;
  }
}

// ---- gather6: 2 mols/wave (independent front chains) + PW/W2T/AAW filler blocks ----
// blocks [0,6250): gather (8 mols/block). [6250,6762): PW. [6762,6826): W2T. [6826,6828): AAW.
__launch_bounds__(256, 4)
__global__ void k_gather6(char* ws, const int* __restrict__ A,
                          const float* __restrict__ m0w, const float* __restrict__ g2,
                          const float* __restrict__ gb2, const float* __restrict__ aa_embed) {
  const int b = blockIdx.x, t = threadIdx.x;
  if (b < 6250) {
    const int lane = t & 63, wid = t >> 6;
    const int molA = b*8 + wid*2, molB = molA + 1;
    const int a_l = lane >> 3, q8 = lane & 7;
    const unsigned char* gm = (const unsigned char*)(ws + GM_OFF);
    const int* cnt = (const int*)(ws + MCNT_OFF);
    const unsigned* rec32 = (const unsigned*)(ws + REC_OFF);
    const unsigned short* rec16 = (const unsigned short*)(ws + REC_OFF);
    const float* EW1 = (const float*)(ws + EW1_OFF);
    const float* TW1 = (const float*)(ws + T_OFF);

    // front loads for BOTH mols, unconditional (A in [0,100) always -> EW1 safe)
    int gmA = gm[molA], gmB = gm[molB];
    int cA = cnt[molA], cB = cnt[molB];
    int aTA = A[molA*8 + a_l], aTB = A[molB*8 + a_l];
    const f32x4* epA = (const f32x4*)(EW1 + aTA*128 + q8*16);
    const f32x4* epB = (const f32x4*)(EW1 + aTB*128 + q8*16);
    f32x4 A0 = epA[0], A1 = epA[1], A2 = epA[2], A3 = epA[3];
    f32x4 B0 = epB[0], B1 = epB[1], B2 = epB[2], B3 = epB[3];
    int nA = gmA ? 0 : (cA < 0 ? 0 : (cA > CAP ? CAP : cA));
    int nB = gmB ? 0 : (cB < 0 ? 0 : (cB > CAP ? CAP : cB));
    if (gmA) { A0 = splat4(0.f); A1 = A0; A2 = A0; A3 = A0; }
    if (gmB) { B0 = splat4(0.f); B1 = B0; B2 = B0; B3 = B0; }

    for (int i = 0; (i + 2 <= nA) | (i + 2 <= nB); i += 2) {   // lockstep pair-iters
      if (i + 2 <= nA) {
        unsigned pr = rec32[molA*20 + (i >> 1)];
        int rv0 = pr & 0xFFFF, rv1 = pr >> 16;
        int p0 = rv0 >> 3, p1 = rv1 >> 3;
        if (p0 < 500 && (rv0 & 7) == a_l) {
          const f32x4* tp = (const f32x4*)(TW1 + p0*128 + q8*16);
          A0 += tp[0]; A1 += tp[1]; A2 += tp[2]; A3 += tp[3];
        }
        if (p1 < 500 && (rv1 & 7) == a_l) {
          const f32x4* tp = (const f32x4*)(TW1 + p1*128 + q8*16);
          A0 += tp[0]; A1 += tp[1]; A2 += tp[2]; A3 += tp[3];
        }
      }
      if (i + 2 <= nB) {
        unsigned pr = rec32[molB*20 + (i >> 1)];
        int rv0 = pr & 0xFFFF, rv1 = pr >> 16;
        int p0 = rv0 >> 3, p1 = rv1 >> 3;
        if (p0 < 500 && (rv0 & 7) == a_l) {
          const f32x4* tp = (const f32x4*)(TW1 + p0*128 + q8*16);
          B0 += tp[0]; B1 += tp[1]; B2 += tp[2]; B3 += tp[3];
        }
        if (p1 < 500 && (rv1 & 7) == a_l) {
          const f32x4* tp = (const f32x4*)(TW1 + p1*128 + q8*16);
          B0 += tp[0]; B1 += tp[1]; B2 += tp[2]; B3 += tp[3];
        }
      }
    }
    if (nA & 1) {
      int rv = rec16[molA*CAP + nA - 1];
      int p = rv >> 3;
      if (p < 500 && (rv & 7) == a_l) {
        const f32x4* tp = (const f32x4*)(TW1 + p*128 + q8*16);
        A0 += tp[0]; A1 += tp[1]; A2 += tp[2]; A3 += tp[3];
      }
    }
    if (nB & 1) {
      int rv = rec16[molB*CAP + nB - 1];
      int p = rv >> 3;
      if (p < 500 && (rv & 7) == a_l) {
        const f32x4* tp = (const f32x4*)(TW1 + p*128 + q8*16);
        B0 += tp[0]; B1 += tp[1]; B2 += tp[2]; B3 += tp[3];
      }
    }
    // relu + cross-atom reduce (lane bits 3..5), both mols
    #pragma unroll
    for (int k = 0; k < 4; ++k) {
      float xa0 = fmaxf(A0[k], 0.f), xa1 = fmaxf(A1[k], 0.f);
      float xa2 = fmaxf(A2[k], 0.f), xa3 = fmaxf(A3[k], 0.f);
      float xb0 = fmaxf(B0[k], 0.f), xb1 = fmaxf(B1[k], 0.f);
      float xb2 = fmaxf(B2[k], 0.f), xb3 = fmaxf(B3[k], 0.f);
      xa0 += __shfl_xor(xa0, 8);  xa1 += __shfl_xor(xa1, 8);
      xa2 += __shfl_xor(xa2, 8);  xa3 += __shfl_xor(xa3, 8);
      xb0 += __shfl_xor(xb0, 8);  xb1 += __shfl_xor(xb1, 8);
      xb2 += __shfl_xor(xb2, 8);  xb3 += __shfl_xor(xb3, 8);
      xa0 += __shfl_xor(xa0, 16); xa1 += __shfl_xor(xa1, 16);
      xa2 += __shfl_xor(xa2, 16); xa3 += __shfl_xor(xa3, 16);
      xb0 += __shfl_xor(xb0, 16); xb1 += __shfl_xor(xb1, 16);
      xb2 += __shfl_xor(xb2, 16); xb3 += __shfl_xor(xb3, 16);
      xa0 += __shfl_xor(xa0, 32); xa1 += __shfl_xor(xa1, 32);
      xa2 += __shfl_xor(xa2, 32); xa3 += __shfl_xor(xa3, 32);
      xb0 += __shfl_xor(xb0, 32); xb1 += __shfl_xor(xb1, 32);
      xb2 += __shfl_xor(xb2, 32); xb3 += __shfl_xor(xb3, 32);
      A0[k] = xa0; A1[k] = xa1; A2[k] = xa2; A3[k] = xa3;
      B0[k] = xb0; B1[k] = xb1; B2[k] = xb2; B3[k] = xb3;
    }
    if (a_l == 0) {
      bf16x8 oA0, oA1, oB0, oB1;
      #pragma unroll
      for (int k = 0; k < 4; ++k) {
        oA0[k] = (__bf16)A0[k]; oA0[k+4] = (__bf16)A1[k];
        oA1[k] = (__bf16)A2[k]; oA1[k+4] = (__bf16)A3[k];
        oB0[k] = (__bf16)B0[k]; oB0[k+4] = (__bf16)B1[k];
        oB1[k] = (__bf16)B2[k]; oB1[k+4] = (__bf16)B3[k];
      }
      char* dA = ws + TOPO_OFF + (long)molA*256 + q8*32;
      char* dB = ws + TOPO_OFF + (long)molB*256 + q8*32;
      *(bf16x8*)dA = oA0; *(bf16x8*)(dA + 16) = oA1;
      *(bf16x8*)dB = oB0; *(bf16x8*)(dB + 16) = oB1;
    }
  } else if (b < 6762) {               // PW: 2 rows/block, 256 thr
    __shared__ float s[256];
    int half = t >> 7, tt = t & 127;
    int p = (b - 6250)*2 + half;
    int c = tt & 63;
    float invf = exp2f((float)c * -0.20762050593046012f);  // 10000^(-c/64)
    float ang = (float)p * invf;
    s[half*128 + tt] = (tt < 64) ? __sinf(ang) : __cosf(ang);
    __syncthreads();
    float acc = 0.f;
    #pragma unroll 4
    for (int j = 0; j < 128; ++j) acc += s[half*128 + j] * m0w[j*128 + tt];
    ((__bf16*)(ws + PW_OFF))[p*128 + tt] = (__bf16)acc;
  } else if (b < 6826) {               // W2T: 2 rows/block
    int half = t >> 7, tt = t & 127;
    int r = (b - 6762)*2 + half;
    float acc = 0.f;
    #pragma unroll 4
    for (int j = 0; j < 128; ++j) acc += g2[r*128 + j] * m0w[(128+j)*128 + tt];
    ((__bf16*)(ws + W2T_OFF))[tt*128 + r] = (__bf16)(acc * RS8);
  } else {                             // AAW: 2 sf/block
    int half = t >> 7, tt = t & 127;
    int sf = (b - 6826)*2 + half, sel = sf & 1, f = sf >> 1;
    float acc = 0.f;
    #pragma unroll 4
    for (int j = 0; j < 128; ++j) acc += aa_embed[sel*128 + j] * m0w[(256+j)*128 + tt];
    if (f) {
      float cacc = 0.f;
      #pragma unroll 4
      for (int j = 0; j < 128; ++j) cacc += gb2[j] * m0w[(128+j)*128 + tt];
      acc += 8.0f * RS8 * cacc;
    }
    ((float*)(ws + AAW_OFF))[sf*128 + tt] = acc;
  }
}

// ------------- GEMM core: 64x128 tile, 4 waves, K=128, single LDS panel -------------
__device__ inline void gemm4(const char* sm, int aoff, const __bf16* wt,
                             const float* bias, int lane, int wave, f32x4 acc[4][2]) {
  const int colA = wave*32 + (lane & 15);
  const int k0   = (lane >> 4) * 8;
  float bb0 = bias[colA], bb1 = bias[colA + 16];
  #pragma unroll
  for (int m = 0; m < 4; ++m) { acc[m][0] = splat4(bb0); acc[m][1] = splat4(bb1); }
  #pragma unroll
  for (int kb = 0; kb < 4; ++kb) {
    bf16x8 b0 = *(const bf16x8*)(wt + colA*128 + kb*32 + k0);
    bf16x8 b1 = *(const bf16x8*)(wt + (colA+16)*128 + kb*32 + k0);
    #pragma unroll
    for (int m = 0; m < 4; ++m) {
      int rA = m*16 + (lane & 15);
      int byte = aoff + rA*256 + (((kb*64) + k0*2) ^ ((rA & 7) << 4));
      bf16x8 a = *(const bf16x8*)(sm + byte);
      acc[m][0] = MFMA(a, b0, acc[m][0]);
      acc[m][1] = MFMA(a, b1, acc[m][1]);
    }
  }
}

__device__ inline void stor4(char* sm, int off, f32x4 acc[4][2],
                             int lane, int wave, bool do_relu) {
  #pragma unroll
  for (int m = 0; m < 4; ++m)
  #pragma unroll
  for (int nf = 0; nf < 2; ++nf)
  #pragma unroll
  for (int r = 0; r < 4; ++r) {
    float v = acc[m][nf][r];
    if (do_relu && v < 0.f) v = 0.f;
    int row = m*16 + (lane >> 4)*4 + r;
    int col = wave*32 + nf*16 + (lane & 15);
    int byte = off + row*256 + ((col*2) ^ ((row & 7) << 4));
    *(__bf16*)(sm + byte) = (__bf16)v;
  }
}

// ---- mlp3: stage topo_pre -> GEMM_T(K=128)+epilogue(PW/AAW) -> GEMM1 -> GEMM3 ----
__launch_bounds__(256)
__global__ void k_mlp3(char* ws, const int* __restrict__ pos_ids,
                       const int* __restrict__ is_aa, const float* cr,
                       const float* mb0, const float* mb1, const float* mb2,
                       float* __restrict__ out) {
  __shared__ __align__(16) char sm[32768];
  const int tid = threadIdx.x, lane = tid & 63, wave = tid >> 6;
  const int r0 = blockIdx.x * 64;
  const unsigned char* gm = (const unsigned char*)(ws + GM_OFF);
  const __bf16* topo_pre = (const __bf16*)(ws + TOPO_OFF);

  for (int i = 0; i < 4; ++i) {          // stage topo panel @0
    int idx = tid + i*256;
    int row = idx >> 4, c = idx & 15;
    int mol = r0 + row;
    bf16x8 v;
    #pragma unroll
    for (int j = 0; j < 8; ++j) v[j] = (__bf16)0.f;
    if (mol < NBLK) v = *(const bf16x8*)(topo_pre + (long)mol*128 + c*8);
    int byte = row*256 + ((c*16) ^ ((row & 7) << 4));
    *(bf16x8*)(sm + byte) = v;
  }
  if (tid < 64) {                        // per-row scalars @16384
    int mol = r0 + tid, packed = 0;
    if (mol < NBLK) {
      int g = gm[mol];
      int corrupt = g && (cr[mol] < 0.1f);
      int sel = corrupt ? 0 : is_aa[mol];
      packed = pos_ids[mol] | (sel << 12) | ((g ? 0 : 1) << 13);
    }
    *(int*)(sm + 16384 + tid*4) = packed;
  }
  __syncthreads();

  f32x4 acc[4][2];
  gemm4(sm, 0, (const __bf16*)(ws + W2T_OFF), mb0, lane, wave, acc);
  {
    const __bf16* PW = (const __bf16*)(ws + PW_OFF);
    const float* AAW = (const float*)(ws + AAW_OFF);
    #pragma unroll
    for (int m = 0; m < 4; ++m)
    #pragma unroll
    for (int r = 0; r < 4; ++r) {
      int row = m*16 + (lane >> 4)*4 + r;
      int packed = *(const int*)(sm + 16384 + row*4);
      int pid = packed & 0xFFF, sf = (packed >> 12) & 3;
      #pragma unroll
      for (int nf = 0; nf < 2; ++nf) {
        int col = wave*32 + nf*16 + (lane & 15);
        float v = acc[m][nf][r] + (float)PW[pid*128 + col] + AAW[sf*128 + col];
        acc[m][nf][r] = fmaxf(v, 0.f);
      }
    }
  }
  __syncthreads();
  stor4(sm, 0, acc, lane, wave, false);  // h1 over topo panel
  __syncthreads();

  gemm4(sm, 0, (const __bf16*)(ws + M1T_OFF), mb1, lane, wave, acc);
  stor4(sm, 16384, acc, lane, wave, true);
  __syncthreads();

  gemm4(sm, 16384, (const __bf16*)(ws + M2T_OFF), mb2, lane, wave, acc);
  #pragma unroll
  for (int m = 0; m < 4; ++m)
  #pragma unroll
  for (int nf = 0; nf < 2; ++nf)
  #pragma unroll
  for (int r = 0; r < 4; ++r) {
    int row = m*16 + (lane >> 4)*4 + r;
    int col = wave*32 + nf*16 + (lane & 15);
    int mol = r0 + row;
    if (mol < NBLK) out[(long)mol*128 + col] = scrub(acc[m][nf][r]);
  }
}

extern "C" void kernel_launch(void* const* d_in, const int* in_sizes, int n_in,
                              void* d_out, int out_size, void* d_ws, size_t ws_size,
                              hipStream_t stream) {
  if (ws_size < WS_NEED) return;   // diagnostic: absmax-fail instead of fault
  const int* A      = (const int*)d_in[0];
  const int* bonds  = (const int*)d_in[1];
  const void* gm    = d_in[3];
  const int* pos    = (const int*)d_in[4];
  const int* isaa   = (const int*)d_in[5];
  const float* cr   = (const float*)d_in[6];
  const float* atom_embed = (const float*)d_in[7];
  const float* bond_embed = (const float*)d_in[8];
  const float* aa_embed   = (const float*)d_in[9];
  const float* g1  = (const float*)d_in[10];
  const float* gb1 = (const float*)d_in[11];
  const float* g2  = (const float*)d_in[12];
  const float* gb2 = (const float*)d_in[13];
  const float* m0  = (const float*)d_in[14];
  const float* mb0 = (const float*)d_in[15];
  const float* m1  = (const float*)d_in[16];
  const float* mb1 = (const float*)d_in[17];
  const float* m2  = (const float*)d_in[18];
  const float* mb2 = (const float*)d_in[19];
  char* ws = (char*)d_ws;

  hipMemsetAsync(ws + MCNT_OFF, 0, (size_t)NBLK*4, stream);
  k_sniff  <<<1, 256, 0, stream>>>(gm, ws);
  k_prep   <<<948, 128, 0, stream>>>(atom_embed, bond_embed, m1, m2,
                                     gm, bonds, A, ws);
  k_prep2  <<<600, 128, 0, stream>>>(atom_embed, g1, gb1, ws);   // EW1, TW1
  k_gather6<<<6828, 256, 0, stream>>>(ws, A, m0, g2, gb2, aa_embed);
  k_mlp3   <<<(NBLK + 63)/64, 256, 0, stream>>>(ws, pos, isaa, cr,
                                                mb0, mb1, mb2, (float*)d_out);
}